// Round 3
// baseline (9938.824 us; speedup 1.0000x reference)
//
#include <hip/hip_runtime.h>
#include <cstdint>
#include <cstddef>

// Problem constants (match reference)
#define A_NUM_ANTS   16384
#define N_NODES      512
#define N_STEPS      511      // NUM_NODES - 1 scan steps
#define N_BATCH      4096

// ---------------------------------------------------------------------------
// Threefry-2x32 (20 rounds), exactly as in jax._src.prng.threefry2x32.
// ---------------------------------------------------------------------------
constexpr uint32_t rotl32(uint32_t x, int r) { return (x << r) | (x >> (32 - r)); }

constexpr void tf2x32(uint32_t k0, uint32_t k1, uint32_t x0, uint32_t x1,
                      uint32_t& o0, uint32_t& o1) {
  const uint32_t k2 = k0 ^ k1 ^ 0x1BD11BDAu;
  x0 += k0; x1 += k1;
  x0 += x1; x1 = rotl32(x1, 13); x1 ^= x0;
  x0 += x1; x1 = rotl32(x1, 15); x1 ^= x0;
  x0 += x1; x1 = rotl32(x1, 26); x1 ^= x0;
  x0 += x1; x1 = rotl32(x1,  6); x1 ^= x0;
  x0 += k1; x1 += k2 + 1u;
  x0 += x1; x1 = rotl32(x1, 17); x1 ^= x0;
  x0 += x1; x1 = rotl32(x1, 29); x1 ^= x0;
  x0 += x1; x1 = rotl32(x1, 16); x1 ^= x0;
  x0 += x1; x1 = rotl32(x1, 24); x1 ^= x0;
  x0 += k2; x1 += k0 + 2u;
  x0 += x1; x1 = rotl32(x1, 13); x1 ^= x0;
  x0 += x1; x1 = rotl32(x1, 15); x1 ^= x0;
  x0 += x1; x1 = rotl32(x1, 26); x1 ^= x0;
  x0 += x1; x1 = rotl32(x1,  6); x1 ^= x0;
  x0 += k0; x1 += k1 + 3u;
  x0 += x1; x1 = rotl32(x1, 17); x1 ^= x0;
  x0 += x1; x1 = rotl32(x1, 29); x1 ^= x0;
  x0 += x1; x1 = rotl32(x1, 16); x1 ^= x0;
  x0 += x1; x1 = rotl32(x1, 24); x1 ^= x0;
  x0 += k1; x1 += k2 + 4u;
  x0 += x1; x1 = rotl32(x1, 13); x1 ^= x0;
  x0 += x1; x1 = rotl32(x1, 15); x1 ^= x0;
  x0 += x1; x1 = rotl32(x1, 26); x1 ^= x0;
  x0 += x1; x1 = rotl32(x1,  6); x1 ^= x0;
  x0 += k2; x1 += k0 + 5u;
  o0 = x0; o1 = x1;
}

// Sequential key-split chain from jax.random.key(42), foldlike split
// (jax_threefry_partitionable=True, modern default):
//   key_{t+1} = TF(key_t, (0,0));  sub_t = TF(key_t, (0,1))
struct Subkeys { uint32_t k0[N_STEPS]; uint32_t k1[N_STEPS]; };

constexpr Subkeys make_subkeys() {
  Subkeys s{};
  uint32_t c0 = 0u, c1 = 42u;          // key data = (hi, lo) of seed 42
  for (int t = 0; t < N_STEPS; ++t) {
    uint32_t n0 = 0, n1 = 0, s0 = 0, s1 = 0;
    tf2x32(c0, c1, 0u, 0u, n0, n1);
    tf2x32(c0, c1, 0u, 1u, s0, s1);
    s.k0[t] = s0; s.k1[t] = s1;
    c0 = n0; c1 = n1;
  }
  return s;
}

namespace { constexpr Subkeys H_SUBKEYS = make_subkeys(); }
__device__ __constant__ Subkeys SUBKEYS = H_SUBKEYS;

#define F32_TINY 1.17549435e-38f

// ---------------------------------------------------------------------------
// Per-ant simulation: one wave per ant; lane l owns nodes l*8..l*8+7.
// Partitionable random_bits: bits(a,n) = w0^w1 of TF(sub_t, (0, a*512+n)).
// Proxy score s = (-log u) * exp(-logit); wave argmin(s,n) == reference's
// argmax(gumbel + logit) with first-index tie-break (monotone transform).
// No fma-contractable float exprs -> bit-identical across both callers.
// ---------------------------------------------------------------------------
template <bool WRITE_PATH>
__device__ __forceinline__ void simulate_ant(
    int a, int lane,
    const float* __restrict__ pher,
    const float* __restrict__ heur,
    int pos,
    float* __restrict__ plen_out,    // [A]   (!WRITE_PATH)
    float* __restrict__ path_out)    // [512] (WRITE_PATH)
{
  float m[8];
  {
    const float* hrow = heur + (size_t)pos * N_NODES;
    const float* prow = pher + (size_t)pos * N_NODES;
#pragma unroll
    for (int q = 0; q < 8; ++q) {
      const int n = lane * 8 + q;
      const float hv = hrow[n];
      const float base = prow[n] * (hv * hv);   // p^1 * h^2
      m[q] = expf(-base);
      if (n == pos) m[q] = 1.0f;                // start node visited: logit 0
    }
  }

  int   cur  = pos;     // lane 0 only
  float plen = 0.0f;    // lane 0 only
  if (WRITE_PATH && lane == 0) path_out[0] = (float)pos;

  const uint32_t ctr_base = (uint32_t)(a * N_NODES + lane * 8);

  for (int t = 0; t < N_STEPS; ++t) {
    const uint32_t k0 = SUBKEYS.k0[t];
    const uint32_t k1 = SUBKEYS.k1[t];

    float bs = 3.4e38f;
    int   bn = 0;
#pragma unroll
    for (int q = 0; q < 8; ++q) {
      uint32_t o0, o1;
      tf2x32(k0, k1, 0u, ctr_base + (uint32_t)q, o0, o1);
      const uint32_t bits = o0 ^ o1;
      const float f = __uint_as_float((bits >> 9) | 0x3f800000u) - 1.0f;
      const float u = fmaxf(F32_TINY, f + F32_TINY);
      const float s = (-logf(u)) * m[q];
      const int n = lane * 8 + q;
      if (q == 0 || s < bs) { bs = s; bn = n; } // ascending n => first-index ties
    }
#pragma unroll
    for (int off = 32; off >= 1; off >>= 1) {
      const float so = __shfl_xor(bs, off, 64);
      const int   no = __shfl_xor(bn, off, 64);
      if (so < bs || (so == bs && no < bn)) { bs = so; bn = no; }
    }
#pragma unroll
    for (int q = 0; q < 8; ++q)
      if (lane * 8 + q == bn) m[q] = 1.0f;      // winner visited: logit -> 0

    if (lane == 0) {
      plen += heur[(size_t)cur * N_NODES + bn]; // exact reference add order
      cur = bn;
      if (WRITE_PATH) path_out[t + 1] = (float)bn;
    }
  }

  if (!WRITE_PATH && lane == 0) plen_out[a] = plen;
}

// Pass 1: all ants, path lengths only.
__global__ __launch_bounds__(256) void aco_sim_kernel(
    const float* __restrict__ pher, const float* __restrict__ heur,
    const int* __restrict__ pos0, float* __restrict__ plen_out, int num_ants)
{
  const int a = (int)((blockIdx.x * blockDim.x + threadIdx.x) >> 6);
  const int lane = threadIdx.x & 63;
  if (a >= num_ants) return;
  simulate_ant<false>(a, lane, pher, heur, pos0[a], plen_out, nullptr);
}

// Pass 2: first-minimum argmin (jnp.argmin semantics), clamped result.
__global__ void aco_argmin_kernel(const float* __restrict__ plen,
                                  int* __restrict__ best, int num_ants) {
  const int tid = threadIdx.x;
  float bv = 3.4e38f;
  int   bi = 0;
  bool  have = false;
  for (int i = tid; i < num_ants; i += 256) {
    const float v = plen[i];
    if (!have || v < bv) { bv = v; bi = i; have = true; }
  }
#pragma unroll
  for (int off = 32; off >= 1; off >>= 1) {
    const float vo = __shfl_xor(bv, off, 64);
    const int   io = __shfl_xor(bi, off, 64);
    if (vo < bv || (vo == bv && io < bi)) { bv = vo; bi = io; }
  }
  __shared__ float sv[4];
  __shared__ int   si[4];
  const int w = tid >> 6;
  if ((tid & 63) == 0) { sv[w] = bv; si[w] = bi; }
  __syncthreads();
  if (tid == 0) {
    for (int j = 1; j < 4; ++j)
      if (sv[j] < bv || (sv[j] == bv && si[j] < bi)) { bv = sv[j]; bi = si[j]; }
    bi = bi < 0 ? 0 : (bi >= num_ants ? num_ants - 1 : bi);  // hard clamp
    *best = bi;
  }
}

// Pass 3: one wave re-simulates ONLY the winning ant -> out[0:512] (row 0).
// Bit-identical draws to pass 1 by construction.
__global__ void aco_resim_kernel(const float* __restrict__ pher,
                                 const float* __restrict__ heur,
                                 const int* __restrict__ pos0,
                                 const int* __restrict__ best,
                                 float* __restrict__ path_out, int num_ants) {
  const int lane = threadIdx.x & 63;
  int a = *best;
  a = a < 0 ? 0 : (a >= num_ants ? num_ants - 1 : a);        // hard clamp
  simulate_ant<true>(a, lane, pher, heur, pos0[a], nullptr, path_out);
}

// Pass 4: copy row 0 -> rows 1..n_rows-1. Row 0 is READ-ONLY here (no race).
__global__ void aco_bcast_kernel(float* __restrict__ out, int total4) {
  const int j = (int)(blockIdx.x * blockDim.x + threadIdx.x);  // over rows 1..
  if (j >= total4) return;
  const int row  = 1 + (j >> 7);          // 128 float4s per 512-float row
  const int col4 = j & 127;
  const float4 v = reinterpret_cast<const float4*>(out)[col4]; // row 0
  reinterpret_cast<float4*>(out)[row * 128 + col4] = v;
}

// ---------------------------------------------------------------------------
extern "C" void kernel_launch(void* const* d_in, const int* in_sizes, int n_in,
                              void* d_out, int out_size, void* d_ws, size_t ws_size,
                              hipStream_t stream) {
  // inputs: 0=x (unused), 1=pheromone_trails f32[512,512],
  //         2=heuristic_info f32[512,512], 3=ant_positions i32[16384]
  const float* pher = (const float*)d_in[1];
  const float* heur = (const float*)d_in[2];
  const int*   pos  = (const int*)d_in[3];
  float* out = (float*)d_out;
  const int num_ants = in_sizes[3];               // 16384

  // d_out doubles as scratch (d_ws untouched):
  //   A: out[0:16384] = plen   B: out[16384] = best (int bits)
  //   C: out[0:512] = winning path (row 0)   D: rows 1.. = copies of row 0
  float* plen = out;
  int*   best = (int*)(out + A_NUM_ANTS);

  const int sim_blocks = (num_ants * 64 + 255) / 256;
  aco_sim_kernel<<<dim3(sim_blocks), dim3(256), 0, stream>>>(
      pher, heur, pos, plen, num_ants);
  aco_argmin_kernel<<<dim3(1), dim3(256), 0, stream>>>(plen, best, num_ants);
  aco_resim_kernel<<<dim3(1), dim3(64), 0, stream>>>(
      pher, heur, pos, best, out, num_ants);
  const int total4 = (out_size - N_NODES) / 4;    // float4s in rows 1..
  aco_bcast_kernel<<<dim3((total4 + 255) / 256), dim3(256), 0, stream>>>(
      out, total4);
}

// Round 4
// 9324.210 us; speedup vs baseline: 1.0659x; 1.0659x over previous
//
#include <hip/hip_runtime.h>
#include <cstdint>
#include <cstddef>

// Problem constants (match reference)
#define A_NUM_ANTS   16384
#define N_NODES      512
#define N_STEPS      511      // NUM_NODES - 1 scan steps
#define N_BATCH      4096

// ---------------------------------------------------------------------------
// Threefry-2x32 (20 rounds), exactly as in jax._src.prng.threefry2x32.
// ---------------------------------------------------------------------------
constexpr uint32_t rotl32(uint32_t x, int r) { return (x << r) | (x >> (32 - r)); }

constexpr void tf2x32(uint32_t k0, uint32_t k1, uint32_t x0, uint32_t x1,
                      uint32_t& o0, uint32_t& o1) {
  const uint32_t k2 = k0 ^ k1 ^ 0x1BD11BDAu;
  x0 += k0; x1 += k1;
  x0 += x1; x1 = rotl32(x1, 13); x1 ^= x0;
  x0 += x1; x1 = rotl32(x1, 15); x1 ^= x0;
  x0 += x1; x1 = rotl32(x1, 26); x1 ^= x0;
  x0 += x1; x1 = rotl32(x1,  6); x1 ^= x0;
  x0 += k1; x1 += k2 + 1u;
  x0 += x1; x1 = rotl32(x1, 17); x1 ^= x0;
  x0 += x1; x1 = rotl32(x1, 29); x1 ^= x0;
  x0 += x1; x1 = rotl32(x1, 16); x1 ^= x0;
  x0 += x1; x1 = rotl32(x1, 24); x1 ^= x0;
  x0 += k2; x1 += k0 + 2u;
  x0 += x1; x1 = rotl32(x1, 13); x1 ^= x0;
  x0 += x1; x1 = rotl32(x1, 15); x1 ^= x0;
  x0 += x1; x1 = rotl32(x1, 26); x1 ^= x0;
  x0 += x1; x1 = rotl32(x1,  6); x1 ^= x0;
  x0 += k0; x1 += k1 + 3u;
  x0 += x1; x1 = rotl32(x1, 17); x1 ^= x0;
  x0 += x1; x1 = rotl32(x1, 29); x1 ^= x0;
  x0 += x1; x1 = rotl32(x1, 16); x1 ^= x0;
  x0 += x1; x1 = rotl32(x1, 24); x1 ^= x0;
  x0 += k1; x1 += k2 + 4u;
  x0 += x1; x1 = rotl32(x1, 13); x1 ^= x0;
  x0 += x1; x1 = rotl32(x1, 15); x1 ^= x0;
  x0 += x1; x1 = rotl32(x1, 26); x1 ^= x0;
  x0 += x1; x1 = rotl32(x1,  6); x1 ^= x0;
  x0 += k2; x1 += k0 + 5u;
  o0 = x0; o1 = x1;
}

// Sequential key-split chain from jax.random.key(42), foldlike split
// (jax_threefry_partitionable=True — CONFIRMED bit-exact in R3):
//   key_{t+1} = TF(key_t, (0,0));  sub_t = TF(key_t, (0,1))
struct Subkeys { uint32_t k0[N_STEPS]; uint32_t k1[N_STEPS]; };

constexpr Subkeys make_subkeys() {
  Subkeys s{};
  uint32_t c0 = 0u, c1 = 42u;          // key data = (hi, lo) of seed 42
  for (int t = 0; t < N_STEPS; ++t) {
    uint32_t n0 = 0, n1 = 0, s0 = 0, s1 = 0;
    tf2x32(c0, c1, 0u, 0u, n0, n1);
    tf2x32(c0, c1, 0u, 1u, s0, s1);
    s.k0[t] = s0; s.k1[t] = s1;
    c0 = n0; c1 = n1;
  }
  return s;
}

namespace { constexpr Subkeys H_SUBKEYS = make_subkeys(); }
__device__ __constant__ Subkeys SUBKEYS = H_SUBKEYS;

#define F32_TINY  1.17549435e-38f
#define NEG_LN2   (-0.69314718056f)

// ---------------------------------------------------------------------------
// Per-ant simulation: one wave per ant; lane l owns nodes l*8..l*8+7.
// Partitionable random_bits: bits(a,n) = w0^w1 of TF(sub_t, (0, a*512+n)).
// Score: reference picks argmax_n(gumbel_n + logit_n); monotone transform:
//   argmax(g+l) == argmin(exp(-(g+l))) == argmin((-log u)*exp(-l))
//               == argmin(log2(u) * (-ln2*exp(-l)))   [global +ln2 scale]
// so per-cell coeff lm = -ln2*exp(-logit), visited cells lm = -ln2 exactly.
// s = __log2f(u)*lm: single v_log_f32 + single mul per cell.
// No fma-contractable float exprs -> bit-identical across both callers.
// ---------------------------------------------------------------------------
template <bool WRITE_PATH>
__device__ __forceinline__ void simulate_ant(
    int a, int lane,
    const float* __restrict__ pher,
    const float* __restrict__ heur,
    int pos,
    float* __restrict__ plen_out,    // [A]   (!WRITE_PATH)
    float* __restrict__ path_out)    // [512] (WRITE_PATH)
{
  float lm[8];   // -ln2 * exp(-logit) per owned cell; visited -> -ln2 exactly
  {
    const float* hrow = heur + (size_t)pos * N_NODES;
    const float* prow = pher + (size_t)pos * N_NODES;
#pragma unroll
    for (int q = 0; q < 8; ++q) {
      const int n = lane * 8 + q;
      const float hv = hrow[n];
      const float base = prow[n] * (hv * hv);   // p^1 * h^2
      lm[q] = NEG_LN2 * expf(-base);
      if (n == pos) lm[q] = NEG_LN2;            // start node visited: logit 0
    }
  }

  int   cur  = pos;     // lane 0 only
  float plen = 0.0f;    // lane 0 only
  if (WRITE_PATH && lane == 0) path_out[0] = (float)pos;

  const uint32_t ctr_base = (uint32_t)(a * N_NODES + lane * 8);

  for (int t = 0; t < N_STEPS; ++t) {
    const uint32_t k0 = SUBKEYS.k0[t];
    const uint32_t k1 = SUBKEYS.k1[t];

    float bs = 3.4e38f;
    int   bn = 0;
#pragma unroll
    for (int q = 0; q < 8; ++q) {
      uint32_t o0, o1;
      tf2x32(k0, k1, 0u, ctr_base + (uint32_t)q, o0, o1);
      const uint32_t bits = o0 ^ o1;
      // u = fmax(f, tiny) == reference's max(tiny, f+tiny) bit-exactly:
      // f = k/2^23 >= 2^-23 absorbs +tiny; f == 0 -> tiny either way.
      const float f = __uint_as_float((bits >> 9) | 0x3f800000u) - 1.0f;
      const float u = fmaxf(f, F32_TINY);
      const float s = __log2f(u) * lm[q];       // v_log_f32 + v_mul
      const int n = lane * 8 + q;
      if (q == 0 || s < bs) { bs = s; bn = n; } // ascending n => first-index ties
    }
#pragma unroll
    for (int off = 32; off >= 1; off >>= 1) {
      const float so = __shfl_xor(bs, off, 64);
      const int   no = __shfl_xor(bn, off, 64);
      if (so < bs || (so == bs && no < bn)) { bs = so; bn = no; }
    }
#pragma unroll
    for (int q = 0; q < 8; ++q)
      if (lane * 8 + q == bn) lm[q] = NEG_LN2;  // winner visited: logit -> 0

    if (lane == 0) {
      plen += heur[(size_t)cur * N_NODES + bn]; // exact reference add order
      cur = bn;
      if (WRITE_PATH) path_out[t + 1] = (float)bn;
    }
  }

  if (!WRITE_PATH && lane == 0) plen_out[a] = plen;
}

// Pass 1: all ants, path lengths only.
__global__ __launch_bounds__(256) void aco_sim_kernel(
    const float* __restrict__ pher, const float* __restrict__ heur,
    const int* __restrict__ pos0, float* __restrict__ plen_out, int num_ants)
{
  const int a = (int)((blockIdx.x * blockDim.x + threadIdx.x) >> 6);
  const int lane = threadIdx.x & 63;
  if (a >= num_ants) return;
  simulate_ant<false>(a, lane, pher, heur, pos0[a], plen_out, nullptr);
}

// Pass 2: first-minimum argmin (jnp.argmin semantics), clamped result.
__global__ void aco_argmin_kernel(const float* __restrict__ plen,
                                  int* __restrict__ best, int num_ants) {
  const int tid = threadIdx.x;
  float bv = 3.4e38f;
  int   bi = 0;
  bool  have = false;
  for (int i = tid; i < num_ants; i += 256) {
    const float v = plen[i];
    if (!have || v < bv) { bv = v; bi = i; have = true; }
  }
#pragma unroll
  for (int off = 32; off >= 1; off >>= 1) {
    const float vo = __shfl_xor(bv, off, 64);
    const int   io = __shfl_xor(bi, off, 64);
    if (vo < bv || (vo == bv && io < bi)) { bv = vo; bi = io; }
  }
  __shared__ float sv[4];
  __shared__ int   si[4];
  const int w = tid >> 6;
  if ((tid & 63) == 0) { sv[w] = bv; si[w] = bi; }
  __syncthreads();
  if (tid == 0) {
    for (int j = 1; j < 4; ++j)
      if (sv[j] < bv || (sv[j] == bv && si[j] < bi)) { bv = sv[j]; bi = si[j]; }
    bi = bi < 0 ? 0 : (bi >= num_ants ? num_ants - 1 : bi);  // hard clamp
    *best = bi;
  }
}

// Pass 3: one wave re-simulates ONLY the winning ant -> out[0:512] (row 0).
// Bit-identical draws to pass 1 by construction.
__global__ void aco_resim_kernel(const float* __restrict__ pher,
                                 const float* __restrict__ heur,
                                 const int* __restrict__ pos0,
                                 const int* __restrict__ best,
                                 float* __restrict__ path_out, int num_ants) {
  const int lane = threadIdx.x & 63;
  int a = *best;
  a = a < 0 ? 0 : (a >= num_ants ? num_ants - 1 : a);        // hard clamp
  simulate_ant<true>(a, lane, pher, heur, pos0[a], nullptr, path_out);
}

// Pass 4: copy row 0 -> rows 1..n_rows-1. Row 0 is READ-ONLY here (no race).
__global__ void aco_bcast_kernel(float* __restrict__ out, int total4) {
  const int j = (int)(blockIdx.x * blockDim.x + threadIdx.x);  // over rows 1..
  if (j >= total4) return;
  const int row  = 1 + (j >> 7);          // 128 float4s per 512-float row
  const int col4 = j & 127;
  const float4 v = reinterpret_cast<const float4*>(out)[col4]; // row 0
  reinterpret_cast<float4*>(out)[row * 128 + col4] = v;
}

// ---------------------------------------------------------------------------
extern "C" void kernel_launch(void* const* d_in, const int* in_sizes, int n_in,
                              void* d_out, int out_size, void* d_ws, size_t ws_size,
                              hipStream_t stream) {
  // inputs: 0=x (unused), 1=pheromone_trails f32[512,512],
  //         2=heuristic_info f32[512,512], 3=ant_positions i32[16384]
  const float* pher = (const float*)d_in[1];
  const float* heur = (const float*)d_in[2];
  const int*   pos  = (const int*)d_in[3];
  float* out = (float*)d_out;
  const int num_ants = in_sizes[3];               // 16384

  // d_out doubles as scratch (d_ws untouched):
  //   A: out[0:16384] = plen   B: out[16384] = best (int bits)
  //   C: out[0:512] = winning path (row 0)   D: rows 1.. = copies of row 0
  float* plen = out;
  int*   best = (int*)(out + A_NUM_ANTS);

  const int sim_blocks = (num_ants * 64 + 255) / 256;
  aco_sim_kernel<<<dim3(sim_blocks), dim3(256), 0, stream>>>(
      pher, heur, pos, plen, num_ants);
  aco_argmin_kernel<<<dim3(1), dim3(256), 0, stream>>>(plen, best, num_ants);
  aco_resim_kernel<<<dim3(1), dim3(64), 0, stream>>>(
      pher, heur, pos, best, out, num_ants);
  const int total4 = (out_size - N_NODES) / 4;    // float4s in rows 1..
  aco_bcast_kernel<<<dim3((total4 + 255) / 256), dim3(256), 0, stream>>>(
      out, total4);
}

// Round 5
// 8845.141 us; speedup vs baseline: 1.1236x; 1.0542x over previous
//
#include <hip/hip_runtime.h>
#include <cstdint>
#include <cstddef>

// Problem constants (match reference)
#define A_NUM_ANTS   16384
#define N_NODES      512
#define N_STEPS      511      // NUM_NODES - 1 scan steps
#define N_BATCH      4096

// ---------------------------------------------------------------------------
// Threefry-2x32 (20 rounds), exactly as in jax._src.prng.threefry2x32.
// ---------------------------------------------------------------------------
constexpr uint32_t rotl32(uint32_t x, int r) { return (x << r) | (x >> (32 - r)); }

constexpr void tf2x32(uint32_t k0, uint32_t k1, uint32_t x0, uint32_t x1,
                      uint32_t& o0, uint32_t& o1) {
  const uint32_t k2 = k0 ^ k1 ^ 0x1BD11BDAu;
  x0 += k0; x1 += k1;
  x0 += x1; x1 = rotl32(x1, 13); x1 ^= x0;
  x0 += x1; x1 = rotl32(x1, 15); x1 ^= x0;
  x0 += x1; x1 = rotl32(x1, 26); x1 ^= x0;
  x0 += x1; x1 = rotl32(x1,  6); x1 ^= x0;
  x0 += k1; x1 += k2 + 1u;
  x0 += x1; x1 = rotl32(x1, 17); x1 ^= x0;
  x0 += x1; x1 = rotl32(x1, 29); x1 ^= x0;
  x0 += x1; x1 = rotl32(x1, 16); x1 ^= x0;
  x0 += x1; x1 = rotl32(x1, 24); x1 ^= x0;
  x0 += k2; x1 += k0 + 2u;
  x0 += x1; x1 = rotl32(x1, 13); x1 ^= x0;
  x0 += x1; x1 = rotl32(x1, 15); x1 ^= x0;
  x0 += x1; x1 = rotl32(x1, 26); x1 ^= x0;
  x0 += x1; x1 = rotl32(x1,  6); x1 ^= x0;
  x0 += k0; x1 += k1 + 3u;
  x0 += x1; x1 = rotl32(x1, 17); x1 ^= x0;
  x0 += x1; x1 = rotl32(x1, 29); x1 ^= x0;
  x0 += x1; x1 = rotl32(x1, 16); x1 ^= x0;
  x0 += x1; x1 = rotl32(x1, 24); x1 ^= x0;
  x0 += k1; x1 += k2 + 4u;
  x0 += x1; x1 = rotl32(x1, 13); x1 ^= x0;
  x0 += x1; x1 = rotl32(x1, 15); x1 ^= x0;
  x0 += x1; x1 = rotl32(x1, 26); x1 ^= x0;
  x0 += x1; x1 = rotl32(x1,  6); x1 ^= x0;
  x0 += k2; x1 += k0 + 5u;
  o0 = x0; o1 = x1;
}

// Sequential key-split chain from jax.random.key(42), foldlike split
// (jax_threefry_partitionable=True — CONFIRMED bit-exact in R3/R4):
//   key_{t+1} = TF(key_t, (0,0));  sub_t = TF(key_t, (0,1))
struct Subkeys { uint32_t k0[N_STEPS]; uint32_t k1[N_STEPS]; };

constexpr Subkeys make_subkeys() {
  Subkeys s{};
  uint32_t c0 = 0u, c1 = 42u;          // key data = (hi, lo) of seed 42
  for (int t = 0; t < N_STEPS; ++t) {
    uint32_t n0 = 0, n1 = 0, s0 = 0, s1 = 0;
    tf2x32(c0, c1, 0u, 0u, n0, n1);
    tf2x32(c0, c1, 0u, 1u, s0, s1);
    s.k0[t] = s0; s.k1[t] = s1;
    c0 = n0; c1 = n1;
  }
  return s;
}

namespace { constexpr Subkeys H_SUBKEYS = make_subkeys(); }
__device__ __constant__ Subkeys SUBKEYS = H_SUBKEYS;

#define NEG_LN2   (-0.69314718056f)

// ---------------------------------------------------------------------------
// Per-ant simulation: one wave per ant; lane l owns nodes l*8..l*8+7.
// Partitionable random_bits: bits(a,n) = w0^w1 of TF(sub_t, (0, a*512+n)).
// Score (identical values to R4, which passed absmax=0):
//   s = __log2f(u) * lm,  lm = -ln2*exp(-logit)  (visited -> -ln2 exactly)
//   argmin(s) == reference argmax(gumbel+logit) by monotone transform.
// R5 changes (reduction only, score values untouched):
//   * dropped fmax(f,TINY): f==0 -> log2 = -inf -> s = +inf, which loses all
//     comparisons exactly as the reference's huge-but-finite score does
//     (that cell winning would need all 511 others > 87 nats: P ~ e^-44000).
//   * index-free min butterfly (ds_bpermute w/ hoisted addrs + v_min_f32),
//     then first-index recovery: lowest matching q per lane (desc cndmask
//     chain), lowest matching lane via ballot+ctz, value via readlane.
//     v_min_f32 propagates exact bits, so equality matching is sound.
// ---------------------------------------------------------------------------
template <bool WRITE_PATH>
__device__ __forceinline__ void simulate_ant(
    int a, int lane,
    const float* __restrict__ pher,
    const float* __restrict__ heur,
    int pos,
    float* __restrict__ plen_out,    // [A]   (!WRITE_PATH)
    float* __restrict__ path_out)    // [512] (WRITE_PATH)
{
  float lm[8];   // -ln2 * exp(-logit) per owned cell; visited -> -ln2 exactly
  {
    const float* hrow = heur + (size_t)pos * N_NODES;
    const float* prow = pher + (size_t)pos * N_NODES;
#pragma unroll
    for (int q = 0; q < 8; ++q) {
      const int n = lane * 8 + q;
      const float hv = hrow[n];
      const float base = prow[n] * (hv * hv);   // p^1 * h^2
      lm[q] = NEG_LN2 * expf(-base);
      if (n == pos) lm[q] = NEG_LN2;            // start node visited: logit 0
    }
  }

  // Hoisted butterfly bpermute byte-addresses (lane^off)<<2.
  int baddr[6];
#pragma unroll
  for (int r = 0; r < 6; ++r) baddr[r] = ((lane ^ (1 << r)) << 2);

  int   cur  = pos;     // wave-uniform
  float plen = 0.0f;    // wave-uniform (redundantly computed by all lanes)
  if (WRITE_PATH && lane == 0) path_out[0] = (float)pos;

  const uint32_t ctr_base = (uint32_t)(a * N_NODES + lane * 8);
  const int lane8 = lane * 8;

  for (int t = 0; t < N_STEPS; ++t) {
    const uint32_t k0 = SUBKEYS.k0[t];
    const uint32_t k1 = SUBKEYS.k1[t];

    float s[8];
#pragma unroll
    for (int q = 0; q < 8; ++q) {
      uint32_t o0, o1;
      tf2x32(k0, k1, 0u, ctr_base + (uint32_t)q, o0, o1);
      const uint32_t bits = o0 ^ o1;
      const float f = __uint_as_float((bits >> 9) | 0x3f800000u) - 1.0f;
      s[q] = __log2f(f) * lm[q];                // >= 0; f==0 -> +inf (loses)
    }
    // lane-local min
    float smin = s[0];
#pragma unroll
    for (int q = 1; q < 8; ++q) smin = fminf(smin, s[q]);
    // wave-wide min butterfly (value-exact propagation)
#pragma unroll
    for (int r = 0; r < 6; ++r) {
      const int other = __builtin_amdgcn_ds_bpermute(baddr[r], __float_as_int(smin));
      smin = fminf(smin, __int_as_float(other));
    }
    // first-index recovery: lowest matching q in this lane
    int fq = 8;
#pragma unroll
    for (int q = 7; q >= 0; --q) if (s[q] == smin) fq = q;
    const unsigned long long mask = __ballot(fq < 8);
    const int winlane = __builtin_ctzll(mask);          // lowest matching lane
    const int bn = __shfl(fq, winlane, 64) + winlane * 8;  // wave-uniform

    // mark winner visited: logit -> 0 => lm -> -ln2 exactly
#pragma unroll
    for (int q = 0; q < 8; ++q)
      if (lane8 + q == bn) lm[q] = NEG_LN2;

    // wave-uniform bookkeeping (exact reference add order)
    plen += heur[(size_t)cur * N_NODES + bn];
    cur = bn;
    if (WRITE_PATH && lane == 0) path_out[t + 1] = (float)bn;
  }

  if (!WRITE_PATH && lane == 0) plen_out[a] = plen;
}

// Pass 1: all ants, path lengths only.
__global__ __launch_bounds__(256, 6) void aco_sim_kernel(
    const float* __restrict__ pher, const float* __restrict__ heur,
    const int* __restrict__ pos0, float* __restrict__ plen_out, int num_ants)
{
  const int a = (int)((blockIdx.x * blockDim.x + threadIdx.x) >> 6);
  const int lane = threadIdx.x & 63;
  if (a >= num_ants) return;
  simulate_ant<false>(a, lane, pher, heur, pos0[a], plen_out, nullptr);
}

// Pass 2: first-minimum argmin (jnp.argmin semantics), clamped result.
__global__ void aco_argmin_kernel(const float* __restrict__ plen,
                                  int* __restrict__ best, int num_ants) {
  const int tid = threadIdx.x;
  float bv = 3.4e38f;
  int   bi = 0;
  bool  have = false;
  for (int i = tid; i < num_ants; i += 256) {
    const float v = plen[i];
    if (!have || v < bv) { bv = v; bi = i; have = true; }
  }
#pragma unroll
  for (int off = 32; off >= 1; off >>= 1) {
    const float vo = __shfl_xor(bv, off, 64);
    const int   io = __shfl_xor(bi, off, 64);
    if (vo < bv || (vo == bv && io < bi)) { bv = vo; bi = io; }
  }
  __shared__ float sv[4];
  __shared__ int   si[4];
  const int w = tid >> 6;
  if ((tid & 63) == 0) { sv[w] = bv; si[w] = bi; }
  __syncthreads();
  if (tid == 0) {
    for (int j = 1; j < 4; ++j)
      if (sv[j] < bv || (sv[j] == bv && si[j] < bi)) { bv = sv[j]; bi = si[j]; }
    bi = bi < 0 ? 0 : (bi >= num_ants ? num_ants - 1 : bi);  // hard clamp
    *best = bi;
  }
}

// Pass 3: one wave re-simulates ONLY the winning ant -> out[0:512] (row 0).
// Bit-identical draws/score sequence to pass 1 (same inlined function; all
// float ops are explicit intrinsics, no reassociation without fast-math).
__global__ void aco_resim_kernel(const float* __restrict__ pher,
                                 const float* __restrict__ heur,
                                 const int* __restrict__ pos0,
                                 const int* __restrict__ best,
                                 float* __restrict__ path_out, int num_ants) {
  const int lane = threadIdx.x & 63;
  int a = *best;
  a = a < 0 ? 0 : (a >= num_ants ? num_ants - 1 : a);        // hard clamp
  simulate_ant<true>(a, lane, pher, heur, pos0[a], nullptr, path_out);
}

// Pass 4: copy row 0 -> rows 1..n_rows-1. Row 0 is READ-ONLY here (no race).
__global__ void aco_bcast_kernel(float* __restrict__ out, int total4) {
  const int j = (int)(blockIdx.x * blockDim.x + threadIdx.x);  // over rows 1..
  if (j >= total4) return;
  const int row  = 1 + (j >> 7);          // 128 float4s per 512-float row
  const int col4 = j & 127;
  const float4 v = reinterpret_cast<const float4*>(out)[col4]; // row 0
  reinterpret_cast<float4*>(out)[row * 128 + col4] = v;
}

// ---------------------------------------------------------------------------
extern "C" void kernel_launch(void* const* d_in, const int* in_sizes, int n_in,
                              void* d_out, int out_size, void* d_ws, size_t ws_size,
                              hipStream_t stream) {
  // inputs: 0=x (unused), 1=pheromone_trails f32[512,512],
  //         2=heuristic_info f32[512,512], 3=ant_positions i32[16384]
  const float* pher = (const float*)d_in[1];
  const float* heur = (const float*)d_in[2];
  const int*   pos  = (const int*)d_in[3];
  float* out = (float*)d_out;
  const int num_ants = in_sizes[3];               // 16384

  // d_out doubles as scratch (d_ws untouched):
  //   A: out[0:16384] = plen   B: out[16384] = best (int bits)
  //   C: out[0:512] = winning path (row 0)   D: rows 1.. = copies of row 0
  float* plen = out;
  int*   best = (int*)(out + A_NUM_ANTS);

  const int sim_blocks = (num_ants * 64 + 255) / 256;
  aco_sim_kernel<<<dim3(sim_blocks), dim3(256), 0, stream>>>(
      pher, heur, pos, plen, num_ants);
  aco_argmin_kernel<<<dim3(1), dim3(256), 0, stream>>>(plen, best, num_ants);
  aco_resim_kernel<<<dim3(1), dim3(64), 0, stream>>>(
      pher, heur, pos, best, out, num_ants);
  const int total4 = (out_size - N_NODES) / 4;    // float4s in rows 1..
  aco_bcast_kernel<<<dim3((total4 + 255) / 256), dim3(256), 0, stream>>>(
      out, total4);
}

// Round 7
// 8505.914 us; speedup vs baseline: 1.1685x; 1.0399x over previous
//
#include <hip/hip_runtime.h>
#include <cstdint>
#include <cstddef>

// Problem constants (match reference)
#define A_NUM_ANTS   16384
#define N_NODES      512
#define N_STEPS      511      // NUM_NODES - 1 scan steps
#define N_BATCH      4096

// ---------------------------------------------------------------------------
// Threefry-2x32 (20 rounds), exactly as in jax._src.prng.threefry2x32.
// ---------------------------------------------------------------------------
constexpr uint32_t rotl32(uint32_t x, int r) { return (x << r) | (x >> (32 - r)); }

constexpr void tf2x32(uint32_t k0, uint32_t k1, uint32_t x0, uint32_t x1,
                      uint32_t& o0, uint32_t& o1) {
  const uint32_t k2 = k0 ^ k1 ^ 0x1BD11BDAu;
  x0 += k0; x1 += k1;
  x0 += x1; x1 = rotl32(x1, 13); x1 ^= x0;
  x0 += x1; x1 = rotl32(x1, 15); x1 ^= x0;
  x0 += x1; x1 = rotl32(x1, 26); x1 ^= x0;
  x0 += x1; x1 = rotl32(x1,  6); x1 ^= x0;
  x0 += k1; x1 += k2 + 1u;
  x0 += x1; x1 = rotl32(x1, 17); x1 ^= x0;
  x0 += x1; x1 = rotl32(x1, 29); x1 ^= x0;
  x0 += x1; x1 = rotl32(x1, 16); x1 ^= x0;
  x0 += x1; x1 = rotl32(x1, 24); x1 ^= x0;
  x0 += k2; x1 += k0 + 2u;
  x0 += x1; x1 = rotl32(x1, 13); x1 ^= x0;
  x0 += x1; x1 = rotl32(x1, 15); x1 ^= x0;
  x0 += x1; x1 = rotl32(x1, 26); x1 ^= x0;
  x0 += x1; x1 = rotl32(x1,  6); x1 ^= x0;
  x0 += k0; x1 += k1 + 3u;
  x0 += x1; x1 = rotl32(x1, 17); x1 ^= x0;
  x0 += x1; x1 = rotl32(x1, 29); x1 ^= x0;
  x0 += x1; x1 = rotl32(x1, 16); x1 ^= x0;
  x0 += x1; x1 = rotl32(x1, 24); x1 ^= x0;
  x0 += k1; x1 += k2 + 4u;
  x0 += x1; x1 = rotl32(x1, 13); x1 ^= x0;
  x0 += x1; x1 = rotl32(x1, 15); x1 ^= x0;
  x0 += x1; x1 = rotl32(x1, 26); x1 ^= x0;
  x0 += x1; x1 = rotl32(x1,  6); x1 ^= x0;
  x0 += k2; x1 += k0 + 5u;
  o0 = x0; o1 = x1;
}

// Sequential key-split chain from jax.random.key(42), foldlike split
// (jax_threefry_partitionable=True — CONFIRMED bit-exact R3..R5):
//   key_{t+1} = TF(key_t, (0,0));  sub_t = TF(key_t, (0,1))
struct Subkeys { uint32_t k0[N_STEPS]; uint32_t k1[N_STEPS]; };

constexpr Subkeys make_subkeys() {
  Subkeys s{};
  uint32_t c0 = 0u, c1 = 42u;          // key data = (hi, lo) of seed 42
  for (int t = 0; t < N_STEPS; ++t) {
    uint32_t n0 = 0, n1 = 0, s0 = 0, s1 = 0;
    tf2x32(c0, c1, 0u, 0u, n0, n1);
    tf2x32(c0, c1, 0u, 1u, s0, s1);
    s.k0[t] = s0; s.k1[t] = s1;
    c0 = n0; c1 = n1;
  }
  return s;
}

namespace { constexpr Subkeys H_SUBKEYS = make_subkeys(); }
__device__ __constant__ Subkeys SUBKEYS = H_SUBKEYS;

#define NEG_LN2   (-0.69314718056f)

// ---------------------------------------------------------------------------
// Per-ant simulation: one wave per ant; lane l owns nodes l*8..l*8+7.
// Partitionable random_bits: bits(a,n) = w0^w1 of TF(sub_t, (0, a*512+n)).
// Exact score (R4/R5, absmax=0-verified): s = __log2f(f)*le, f = u's mantissa
// float, le = -ln2*exp(-logit) (visited -> -ln2). argmin(s) == ref argmax.
//
// R6/R7: integer candidate filter. s = L*|le| with L = -log2(u) monotone in
// m = bits>>9, and |le| in a band of relative width ratio-1 (~1e-3, computed
// from the actual inputs at setup). Any possible winner has
//   L <= L(m_max) * ratio,
// so m >= m_thr where m_thr is computed once per step with conservative
// rounding (allow = ratio*(1+2e-4); final *(1-1e-4) down-slack in m-space
// dominates the ~2e-6 rel error of v_log_f32/v_exp_f32; integer truncation
// rounds down). If exactly ONE cell passes -> it IS the winner (pure
// SALU extraction, no float math). Else (~0.2% of steps) -> exact R5 path,
// bit-identical score formula, same first-index tie-break.
// ---------------------------------------------------------------------------
template <bool WRITE_PATH>
__device__ __forceinline__ void simulate_ant(
    int a, int lane,
    const float* __restrict__ pher,
    const float* __restrict__ heur,
    int pos,
    float* __restrict__ plen_out,    // [A]   (!WRITE_PATH)
    float* __restrict__ path_out)    // [512] (WRITE_PATH)
{
  float    lm[8];        // UNVISITED coeff -ln2*exp(-base); never modified
  uint32_t visited = 0;  // bit q: cell lane*8+q visited
  float    ebmin, ebmax; // range of exp(-base) across wave, incl 1.0 (visited)
  {
    const float* hrow = heur + (size_t)pos * N_NODES;
    const float* prow = pher + (size_t)pos * N_NODES;
    ebmin = 1.0f; ebmax = 1.0f;   // include visited value exp(0)=1
#pragma unroll
    for (int q = 0; q < 8; ++q) {
      const int n = lane * 8 + q;
      const float hv = hrow[n];
      const float base = prow[n] * (hv * hv);   // p^1 * h^2
      const float eb = expf(-base);
      lm[q] = NEG_LN2 * eb;
      ebmin = fminf(ebmin, eb);
      ebmax = fmaxf(ebmax, eb);
      if (n == pos) visited |= (1u << q);       // start node visited
    }
  }

  // Hoisted butterfly bpermute byte-addresses (lane^off)<<2.
  int baddr[6];
#pragma unroll
  for (int r = 0; r < 6; ++r) baddr[r] = ((lane ^ (1 << r)) << 2);

  // Wave-wide eb range -> conservative allow factor (one-time).
#pragma unroll
  for (int r = 0; r < 6; ++r) {
    ebmin = fminf(ebmin, __int_as_float(
        __builtin_amdgcn_ds_bpermute(baddr[r], __float_as_int(ebmin))));
    ebmax = fmaxf(ebmax, __int_as_float(
        __builtin_amdgcn_ds_bpermute(baddr[r], __float_as_int(ebmax))));
  }
  const float allow = (ebmax / ebmin) * (1.0f + 2e-4f);  // >= 1, wave-uniform

  int   cur  = pos;     // wave-uniform
  float plen = 0.0f;    // wave-uniform (redundantly computed by all lanes)
  if (WRITE_PATH && lane == 0) path_out[0] = (float)pos;

  const uint32_t ctr_base = (uint32_t)(a * N_NODES + lane * 8);

  for (int t = 0; t < N_STEPS; ++t) {
    const uint32_t k0 = SUBKEYS.k0[t];
    const uint32_t k1 = SUBKEYS.k1[t];

    uint32_t m[8];
#pragma unroll
    for (int q = 0; q < 8; ++q) {
      uint32_t o0, o1;
      tf2x32(k0, k1, 0u, ctr_base + (uint32_t)q, o0, o1);
      m[q] = (o0 ^ o1) >> 9;                    // u's 23-bit mantissa (int)
    }
    // wave max of m
    uint32_t mmax = m[0];
#pragma unroll
    for (int q = 1; q < 8; ++q) mmax = mmax > m[q] ? mmax : m[q];
#pragma unroll
    for (int r = 0; r < 6; ++r) {
      const uint32_t o = (uint32_t)__builtin_amdgcn_ds_bpermute(baddr[r], (int)mmax);
      mmax = mmax > o ? mmax : o;
    }
    // conservative integer threshold (wave-uniform, ~9 VALU incl 2 trans)
    const float L    = 23.0f - __log2f((float)mmax);       // -log2(u_max) >= 0
    const float uthr = __builtin_amdgcn_exp2f(-L * allow); // v_exp_f32
    const uint32_t mthr = (uint32_t)(uthr * 8388608.0f * (1.0f - 1e-4f));

    // candidate ballots (8 v_cmp; popcounts/sums on SALU)
    unsigned long long b[8];
    int tot = 0;
#pragma unroll
    for (int q = 0; q < 8; ++q) {
      b[q] = __ballot(m[q] >= mthr);
      tot += __popcll(b[q]);
    }

    int bn;
    if (tot == 1) {
      // unique filter-passer == winner; pure SALU index extraction
      bn = 0;
#pragma unroll
      for (int q = 0; q < 8; ++q)
        if (b[q]) bn = (int)__builtin_ctzll(b[q]) * 8 + q;
    } else {
      // exact path — bit-identical to R5 (verified absmax=0)
      float s[8];
#pragma unroll
      for (int q = 0; q < 8; ++q) {
        const float f  = __uint_as_float(m[q] | 0x3f800000u) - 1.0f;
        const float le = ((visited >> q) & 1u) ? NEG_LN2 : lm[q];
        s[q] = __log2f(f) * le;                 // >= 0; f==0 -> +inf (loses)
      }
      float smin = s[0];
#pragma unroll
      for (int q = 1; q < 8; ++q) smin = fminf(smin, s[q]);
#pragma unroll
      for (int r = 0; r < 6; ++r)
        smin = fminf(smin, __int_as_float(
            __builtin_amdgcn_ds_bpermute(baddr[r], __float_as_int(smin))));
      int fq = 8;
#pragma unroll
      for (int q = 7; q >= 0; --q) if (s[q] == smin) fq = q;
      const unsigned long long mask = __ballot(fq < 8);
      const int winlane = __builtin_ctzll(mask);        // lowest matching lane
      bn = __shfl(fq, winlane, 64) + winlane * 8;       // lowest n overall
    }

    // mark winner visited (wave-uniform bn)
    if ((bn >> 3) == lane) visited |= (1u << (bn & 7));

    // wave-uniform bookkeeping (exact reference add order)
    plen += heur[(size_t)cur * N_NODES + bn];
    cur = bn;
    if (WRITE_PATH && lane == 0) path_out[t + 1] = (float)bn;
  }

  if (!WRITE_PATH && lane == 0) plen_out[a] = plen;
}

// Pass 1: all ants, path lengths only.
__global__ __launch_bounds__(256, 6) void aco_sim_kernel(
    const float* __restrict__ pher, const float* __restrict__ heur,
    const int* __restrict__ pos0, float* __restrict__ plen_out, int num_ants)
{
  const int a = (int)((blockIdx.x * blockDim.x + threadIdx.x) >> 6);
  const int lane = threadIdx.x & 63;
  if (a >= num_ants) return;
  simulate_ant<false>(a, lane, pher, heur, pos0[a], plen_out, nullptr);
}

// Pass 2: first-minimum argmin (jnp.argmin semantics), clamped result.
__global__ void aco_argmin_kernel(const float* __restrict__ plen,
                                  int* __restrict__ best, int num_ants) {
  const int tid = threadIdx.x;
  float bv = 3.4e38f;
  int   bi = 0;
  bool  have = false;
  for (int i = tid; i < num_ants; i += 256) {
    const float v = plen[i];
    if (!have || v < bv) { bv = v; bi = i; have = true; }
  }
#pragma unroll
  for (int off = 32; off >= 1; off >>= 1) {
    const float vo = __shfl_xor(bv, off, 64);
    const int   io = __shfl_xor(bi, off, 64);
    if (vo < bv || (vo == bv && io < bi)) { bv = vo; bi = io; }
  }
  __shared__ float sv[4];
  __shared__ int   si[4];
  const int w = tid >> 6;
  if ((tid & 63) == 0) { sv[w] = bv; si[w] = bi; }
  __syncthreads();
  if (tid == 0) {
    for (int j = 1; j < 4; ++j)
      if (sv[j] < bv || (sv[j] == bv && si[j] < bi)) { bv = sv[j]; bi = si[j]; }
    bi = bi < 0 ? 0 : (bi >= num_ants ? num_ants - 1 : bi);  // hard clamp
    *best = bi;
  }
}

// Pass 3: one wave re-simulates ONLY the winning ant -> out[0:512] (row 0).
// Bit-identical draws/filter/scores to pass 1 (same inlined function).
__global__ void aco_resim_kernel(const float* __restrict__ pher,
                                 const float* __restrict__ heur,
                                 const int* __restrict__ pos0,
                                 const int* __restrict__ best,
                                 float* __restrict__ path_out, int num_ants) {
  const int lane = threadIdx.x & 63;
  int a = *best;
  a = a < 0 ? 0 : (a >= num_ants ? num_ants - 1 : a);        // hard clamp
  simulate_ant<true>(a, lane, pher, heur, pos0[a], nullptr, path_out);
}

// Pass 4: copy row 0 -> rows 1..n_rows-1. Row 0 is READ-ONLY here (no race).
__global__ void aco_bcast_kernel(float* __restrict__ out, int total4) {
  const int j = (int)(blockIdx.x * blockDim.x + threadIdx.x);  // over rows 1..
  if (j >= total4) return;
  const int row  = 1 + (j >> 7);          // 128 float4s per 512-float row
  const int col4 = j & 127;
  const float4 v = reinterpret_cast<const float4*>(out)[col4]; // row 0
  reinterpret_cast<float4*>(out)[row * 128 + col4] = v;
}

// ---------------------------------------------------------------------------
extern "C" void kernel_launch(void* const* d_in, const int* in_sizes, int n_in,
                              void* d_out, int out_size, void* d_ws, size_t ws_size,
                              hipStream_t stream) {
  // inputs: 0=x (unused), 1=pheromone_trails f32[512,512],
  //         2=heuristic_info f32[512,512], 3=ant_positions i32[16384]
  const float* pher = (const float*)d_in[1];
  const float* heur = (const float*)d_in[2];
  const int*   pos  = (const int*)d_in[3];
  float* out = (float*)d_out;
  const int num_ants = in_sizes[3];               // 16384

  // d_out doubles as scratch (d_ws untouched):
  //   A: out[0:16384] = plen   B: out[16384] = best (int bits)
  //   C: out[0:512] = winning path (row 0)   D: rows 1.. = copies of row 0
  float* plen = out;
  int*   best = (int*)(out + A_NUM_ANTS);

  const int sim_blocks = (num_ants * 64 + 255) / 256;
  aco_sim_kernel<<<dim3(sim_blocks), dim3(256), 0, stream>>>(
      pher, heur, pos, plen, num_ants);
  aco_argmin_kernel<<<dim3(1), dim3(256), 0, stream>>>(plen, best, num_ants);
  aco_resim_kernel<<<dim3(1), dim3(64), 0, stream>>>(
      pher, heur, pos, best, out, num_ants);
  const int total4 = (out_size - N_NODES) / 4;    // float4s in rows 1..
  aco_bcast_kernel<<<dim3((total4 + 255) / 256), dim3(256), 0, stream>>>(
      out, total4);
}

// Round 8
// 8384.428 us; speedup vs baseline: 1.1854x; 1.0145x over previous
//
#include <hip/hip_runtime.h>
#include <cstdint>
#include <cstddef>

// Problem constants (match reference)
#define A_NUM_ANTS   16384
#define N_NODES      512
#define N_STEPS      511      // NUM_NODES - 1 scan steps
#define N_BATCH      4096

// ---------------------------------------------------------------------------
// Threefry-2x32 (20 rounds), exactly as in jax._src.prng.threefry2x32.
// ---------------------------------------------------------------------------
constexpr uint32_t rotl32(uint32_t x, int r) { return (x << r) | (x >> (32 - r)); }

constexpr void tf2x32(uint32_t k0, uint32_t k1, uint32_t x0, uint32_t x1,
                      uint32_t& o0, uint32_t& o1) {
  const uint32_t k2 = k0 ^ k1 ^ 0x1BD11BDAu;
  x0 += k0; x1 += k1;
  x0 += x1; x1 = rotl32(x1, 13); x1 ^= x0;
  x0 += x1; x1 = rotl32(x1, 15); x1 ^= x0;
  x0 += x1; x1 = rotl32(x1, 26); x1 ^= x0;
  x0 += x1; x1 = rotl32(x1,  6); x1 ^= x0;
  x0 += k1; x1 += k2 + 1u;
  x0 += x1; x1 = rotl32(x1, 17); x1 ^= x0;
  x0 += x1; x1 = rotl32(x1, 29); x1 ^= x0;
  x0 += x1; x1 = rotl32(x1, 16); x1 ^= x0;
  x0 += x1; x1 = rotl32(x1, 24); x1 ^= x0;
  x0 += k2; x1 += k0 + 2u;
  x0 += x1; x1 = rotl32(x1, 13); x1 ^= x0;
  x0 += x1; x1 = rotl32(x1, 15); x1 ^= x0;
  x0 += x1; x1 = rotl32(x1, 26); x1 ^= x0;
  x0 += x1; x1 = rotl32(x1,  6); x1 ^= x0;
  x0 += k0; x1 += k1 + 3u;
  x0 += x1; x1 = rotl32(x1, 17); x1 ^= x0;
  x0 += x1; x1 = rotl32(x1, 29); x1 ^= x0;
  x0 += x1; x1 = rotl32(x1, 16); x1 ^= x0;
  x0 += x1; x1 = rotl32(x1, 24); x1 ^= x0;
  x0 += k1; x1 += k2 + 4u;
  x0 += x1; x1 = rotl32(x1, 13); x1 ^= x0;
  x0 += x1; x1 = rotl32(x1, 15); x1 ^= x0;
  x0 += x1; x1 = rotl32(x1, 26); x1 ^= x0;
  x0 += x1; x1 = rotl32(x1,  6); x1 ^= x0;
  x0 += k2; x1 += k0 + 5u;
  o0 = x0; o1 = x1;
}

// Sequential key-split chain from jax.random.key(42), foldlike split
// (jax_threefry_partitionable=True — CONFIRMED bit-exact R3..R7):
//   key_{t+1} = TF(key_t, (0,0));  sub_t = TF(key_t, (0,1))
struct Subkeys { uint32_t k0[N_STEPS]; uint32_t k1[N_STEPS]; };

constexpr Subkeys make_subkeys() {
  Subkeys s{};
  uint32_t c0 = 0u, c1 = 42u;          // key data = (hi, lo) of seed 42
  for (int t = 0; t < N_STEPS; ++t) {
    uint32_t n0 = 0, n1 = 0, s0 = 0, s1 = 0;
    tf2x32(c0, c1, 0u, 0u, n0, n1);
    tf2x32(c0, c1, 0u, 1u, s0, s1);
    s.k0[t] = s0; s.k1[t] = s1;
    c0 = n0; c1 = n1;
  }
  return s;
}

namespace { constexpr Subkeys H_SUBKEYS = make_subkeys(); }
__device__ __constant__ Subkeys SUBKEYS = H_SUBKEYS;

#define NEG_LN2   (-0.69314718056f)

struct Frag { uint32_t m[8]; };   // per-lane mantissas of the 8 owned cells

// ---------------------------------------------------------------------------
// Per-ant simulation: one wave per ant; lane l owns nodes l*8..l*8+7.
// Partitionable random_bits: bits(a,n) = w0^w1 of TF(sub_t, (0, a*512+n)).
// Exact score (R4..R7, absmax=0-verified): s = __log2f(f)*le with
// f = m*2^-23 exactly, le = -ln2*exp(-logit) (visited -> -ln2);
// argmin(s) == ref argmax(gumbel+logit), first-index ties.
//
// R8 filter (integer/SALU, strictly more conservative than R7's float one):
// keep cell iff m >= mthr where true bound is T = mmax*2^{-delta*E},
// E = 23-log2(mmax) = -log2(u_max). For u_max >= 0.5 (g = 1-u <= 0.5):
//   mmax - T <= mmax*delta*E*ln2 <= delta*d*(1+g)*(1-g) <= 1.5*delta*d,
//   d = 2^23 - mmax. So mthr = mmax - (umulhi(D32,d)+2),
//   D32 = (uint)(1.5*delta*2^32)+1, delta = ratio*(1+3e-4)-1+1e-5 padded to
//   dominate all v_log/v_exp/div ulp effects (>=200x margin) plus -2 abs.
// mmax < 2^22 or delta unusable -> mthr = UINT_MAX -> slow path (P ~ 0).
// Unique passer -> winner (SALU extraction). Else exact R5 float path.
//
// R8 pipeline: step t+1's hashes are independent of step t's outcome ->
// compute them in the same basic block as t's reduction (double-buffered
// Frags, 2x-unrolled loop) so the scheduler fills bpermute-wait bubbles.
// ---------------------------------------------------------------------------
template <bool WRITE_PATH>
__device__ __forceinline__ void simulate_ant(
    int a, int lane,
    const float* __restrict__ pher,
    const float* __restrict__ heur,
    int pos,
    float* __restrict__ plen_out,    // [A]   (!WRITE_PATH)
    float* __restrict__ path_out)    // [512] (WRITE_PATH)
{
  float    lm[8];        // UNVISITED coeff -ln2*exp(-base); never modified
  uint32_t visited = 0;  // bit q: cell lane*8+q visited
  float    ebmin, ebmax; // range of exp(-base) across wave, incl 1.0 (visited)
  {
    const float* hrow = heur + (size_t)pos * N_NODES;
    const float* prow = pher + (size_t)pos * N_NODES;
    ebmin = 1.0f; ebmax = 1.0f;   // include visited value exp(0)=1
#pragma unroll
    for (int q = 0; q < 8; ++q) {
      const int n = lane * 8 + q;
      const float hv = hrow[n];
      const float base = prow[n] * (hv * hv);   // p^1 * h^2
      const float eb = expf(-base);
      lm[q] = NEG_LN2 * eb;
      ebmin = fminf(ebmin, eb);
      ebmax = fmaxf(ebmax, eb);
      if (n == pos) visited |= (1u << q);       // start node visited
    }
  }

  // Hoisted butterfly bpermute byte-addresses (lane^off)<<2.
  int baddr[6];
#pragma unroll
  for (int r = 0; r < 6; ++r) baddr[r] = ((lane ^ (1 << r)) << 2);

  // Wave-wide eb range -> conservative integer-filter slope (one-time).
#pragma unroll
  for (int r = 0; r < 6; ++r) {
    ebmin = fminf(ebmin, __int_as_float(
        __builtin_amdgcn_ds_bpermute(baddr[r], __float_as_int(ebmin))));
    ebmax = fmaxf(ebmax, __int_as_float(
        __builtin_amdgcn_ds_bpermute(baddr[r], __float_as_int(ebmax))));
  }
  const float ratio = ebmax / ebmin;                       // >= 1
  const float delta = ratio * (1.0f + 3e-4f) - 1.0f + 1e-5f;
  const float d15   = delta * 1.5f;
  const bool  always_slow = !(d15 < 0.4f);                 // also catches NaN
  const uint32_t D32 = always_slow ? 0xFFFFFFFFu
                     : ((uint32_t)(d15 * 4294967296.0f) + 1u);

  int   cur  = pos;     // wave-uniform
  float plen = 0.0f;    // wave-uniform (redundantly computed by all lanes)
  if (WRITE_PATH && lane == 0) path_out[0] = (float)pos;

  const uint32_t ctr_base = (uint32_t)(a * N_NODES + lane * 8);

  // 8 hashes for one step -> mantissas
  auto hash8 = [&](Frag& f, int t) __attribute__((always_inline)) {
    const uint32_t k0 = SUBKEYS.k0[t];
    const uint32_t k1 = SUBKEYS.k1[t];
#pragma unroll
    for (int q = 0; q < 8; ++q) {
      uint32_t o0, o1;
      tf2x32(k0, k1, 0u, ctr_base + (uint32_t)q, o0, o1);
      f.m[q] = (o0 ^ o1) >> 9;                  // u's 23-bit mantissa (int)
    }
  };

  // one simulation step using `use`; optionally prefetch hashes for step
  // tpre into `pre` (independent work placed in the same BB for scheduling)
  auto step = [&](Frag& use, Frag& pre, int t, int tpre, bool do_pre)
      __attribute__((always_inline)) {
    // wave max of m
    uint32_t mmax = use.m[0];
#pragma unroll
    for (int q = 1; q < 8; ++q) mmax = mmax > use.m[q] ? mmax : use.m[q];
#pragma unroll
    for (int r = 0; r < 6; ++r) {
      const uint32_t o = (uint32_t)__builtin_amdgcn_ds_bpermute(baddr[r], (int)mmax);
      mmax = mmax > o ? mmax : o;
    }

    if (do_pre) hash8(pre, tpre);   // fills the bpermute-wait bubbles

    // integer threshold, SALU after readfirstlane (wave-uniform)
    const uint32_t mmax_s = (uint32_t)__builtin_amdgcn_readfirstlane((int)mmax);
    const uint32_t d   = 8388608u - mmax_s;
    const uint32_t sub = __umulhi(D32, d) + 2u;
    uint32_t mthr = mmax_s - sub;               // wrap -> huge -> slow path
    if (always_slow || mmax_s < 4194304u) mthr = 0xFFFFFFFFu;

    // candidate ballots (8 v_cmp; popcounts/sums on SALU)
    unsigned long long b[8];
    int tot = 0;
#pragma unroll
    for (int q = 0; q < 8; ++q) {
      b[q] = __ballot(use.m[q] >= mthr);
      tot += __popcll(b[q]);
    }

    int bn;
    if (tot == 1) {
      // unique filter-passer == winner; pure SALU index extraction
      bn = 0;
#pragma unroll
      for (int q = 0; q < 8; ++q)
        if (b[q]) bn = (int)__builtin_ctzll(b[q]) * 8 + q;
    } else {
      // exact path — bit-identical to R5/R7 (verified absmax=0)
      float s[8];
#pragma unroll
      for (int q = 0; q < 8; ++q) {
        const float f  = __uint_as_float(use.m[q] | 0x3f800000u) - 1.0f;
        const float le = ((visited >> q) & 1u) ? NEG_LN2 : lm[q];
        s[q] = __log2f(f) * le;                 // >= 0; f==0 -> +inf (loses)
      }
      float smin = s[0];
#pragma unroll
      for (int q = 1; q < 8; ++q) smin = fminf(smin, s[q]);
#pragma unroll
      for (int r = 0; r < 6; ++r)
        smin = fminf(smin, __int_as_float(
            __builtin_amdgcn_ds_bpermute(baddr[r], __float_as_int(smin))));
      int fq = 8;
#pragma unroll
      for (int q = 7; q >= 0; --q) if (s[q] == smin) fq = q;
      const unsigned long long mask = __ballot(fq < 8);
      const int winlane = __builtin_ctzll(mask);        // lowest matching lane
      bn = __shfl(fq, winlane, 64) + winlane * 8;       // lowest n overall
    }

    // mark winner visited (wave-uniform bn)
    if ((bn >> 3) == lane) visited |= (1u << (bn & 7));

    // wave-uniform bookkeeping (exact reference add order)
    plen += heur[(size_t)cur * N_NODES + bn];
    cur = bn;
    if (WRITE_PATH && lane == 0) path_out[t + 1] = (float)bn;
  };

  Frag A, B;
  hash8(A, 0);                                   // prologue
  for (int tt = 0; tt < (N_STEPS - 1) / 2; ++tt) {   // 255 pairs: t=0..509
    const int t0 = 2 * tt;
    step(A, B, t0,     t0 + 1, true);
    step(B, A, t0 + 1, t0 + 2, true);
  }
  step(A, B, N_STEPS - 1, 0, false);             // t=510, no prefetch

  if (!WRITE_PATH && lane == 0) plen_out[a] = plen;
}

// Pass 1: all ants, path lengths only.
__global__ __launch_bounds__(256, 6) void aco_sim_kernel(
    const float* __restrict__ pher, const float* __restrict__ heur,
    const int* __restrict__ pos0, float* __restrict__ plen_out, int num_ants)
{
  const int a = (int)((blockIdx.x * blockDim.x + threadIdx.x) >> 6);
  const int lane = threadIdx.x & 63;
  if (a >= num_ants) return;
  simulate_ant<false>(a, lane, pher, heur, pos0[a], plen_out, nullptr);
}

// Pass 2: first-minimum argmin (jnp.argmin semantics), clamped result.
__global__ void aco_argmin_kernel(const float* __restrict__ plen,
                                  int* __restrict__ best, int num_ants) {
  const int tid = threadIdx.x;
  float bv = 3.4e38f;
  int   bi = 0;
  bool  have = false;
  for (int i = tid; i < num_ants; i += 256) {
    const float v = plen[i];
    if (!have || v < bv) { bv = v; bi = i; have = true; }
  }
#pragma unroll
  for (int off = 32; off >= 1; off >>= 1) {
    const float vo = __shfl_xor(bv, off, 64);
    const int   io = __shfl_xor(bi, off, 64);
    if (vo < bv || (vo == bv && io < bi)) { bv = vo; bi = io; }
  }
  __shared__ float sv[4];
  __shared__ int   si[4];
  const int w = tid >> 6;
  if ((tid & 63) == 0) { sv[w] = bv; si[w] = bi; }
  __syncthreads();
  if (tid == 0) {
    for (int j = 1; j < 4; ++j)
      if (sv[j] < bv || (sv[j] == bv && si[j] < bi)) { bv = sv[j]; bi = si[j]; }
    bi = bi < 0 ? 0 : (bi >= num_ants ? num_ants - 1 : bi);  // hard clamp
    *best = bi;
  }
}

// Pass 3: one wave re-simulates ONLY the winning ant -> out[0:512] (row 0).
// Bit-identical draws/filter/scores to pass 1 (same inlined function).
__global__ void aco_resim_kernel(const float* __restrict__ pher,
                                 const float* __restrict__ heur,
                                 const int* __restrict__ pos0,
                                 const int* __restrict__ best,
                                 float* __restrict__ path_out, int num_ants) {
  const int lane = threadIdx.x & 63;
  int a = *best;
  a = a < 0 ? 0 : (a >= num_ants ? num_ants - 1 : a);        // hard clamp
  simulate_ant<true>(a, lane, pher, heur, pos0[a], nullptr, path_out);
}

// Pass 4: copy row 0 -> rows 1..n_rows-1. Row 0 is READ-ONLY here (no race).
__global__ void aco_bcast_kernel(float* __restrict__ out, int total4) {
  const int j = (int)(blockIdx.x * blockDim.x + threadIdx.x);  // over rows 1..
  if (j >= total4) return;
  const int row  = 1 + (j >> 7);          // 128 float4s per 512-float row
  const int col4 = j & 127;
  const float4 v = reinterpret_cast<const float4*>(out)[col4]; // row 0
  reinterpret_cast<float4*>(out)[row * 128 + col4] = v;
}

// ---------------------------------------------------------------------------
extern "C" void kernel_launch(void* const* d_in, const int* in_sizes, int n_in,
                              void* d_out, int out_size, void* d_ws, size_t ws_size,
                              hipStream_t stream) {
  // inputs: 0=x (unused), 1=pheromone_trails f32[512,512],
  //         2=heuristic_info f32[512,512], 3=ant_positions i32[16384]
  const float* pher = (const float*)d_in[1];
  const float* heur = (const float*)d_in[2];
  const int*   pos  = (const int*)d_in[3];
  float* out = (float*)d_out;
  const int num_ants = in_sizes[3];               // 16384

  // d_out doubles as scratch (d_ws untouched):
  //   A: out[0:16384] = plen   B: out[16384] = best (int bits)
  //   C: out[0:512] = winning path (row 0)   D: rows 1.. = copies of row 0
  float* plen = out;
  int*   best = (int*)(out + A_NUM_ANTS);

  const int sim_blocks = (num_ants * 64 + 255) / 256;
  aco_sim_kernel<<<dim3(sim_blocks), dim3(256), 0, stream>>>(
      pher, heur, pos, plen, num_ants);
  aco_argmin_kernel<<<dim3(1), dim3(256), 0, stream>>>(plen, best, num_ants);
  aco_resim_kernel<<<dim3(1), dim3(64), 0, stream>>>(
      pher, heur, pos, best, out, num_ants);
  const int total4 = (out_size - N_NODES) / 4;    // float4s in rows 1..
  aco_bcast_kernel<<<dim3((total4 + 255) / 256), dim3(256), 0, stream>>>(
      out, total4);
}